// Round 7
// baseline (430.600 us; speedup 1.0000x reference)
//
#include <hip/hip_runtime.h>
#include <hip/hip_bf16.h>

typedef __attribute__((ext_vector_type(8))) short short8;
typedef __attribute__((ext_vector_type(4))) float float4v;

#define NB 32
#define LL 128
#define DDIM 300
#define DP 320
#define KDIM 50
#define TP 40    // Tt pitch (bf16 elems), 80B rows, 16B-aligned
#define SLAB_OFF 18759680ull
#define WS_NEED  (18759680ull + 104857600ull)

__device__ __forceinline__ unsigned short f2bf(float x) {
    unsigned int u = __float_as_uint(x);
    unsigned int r = (u + 0x7FFFu + ((u >> 16) & 1u)) >> 16;
    return (unsigned short)r;
}
__device__ __forceinline__ unsigned int pack2bf(float a, float b) {
    return (unsigned int)f2bf(a) | ((unsigned int)f2bf(b) << 16);
}
__device__ __forceinline__ float4v mfma16(short8 a, short8 b, float4v c) {
    return __builtin_amdgcn_mfma_f32_16x16x32_bf16(a, b, c, 0, 0, 0);
}

// ---------- fused prep: one launch, three arms ----------
// [0,1280): e1/e2 -> bf16 padded    [1280,1780): Wb -> Wbt[k][e][d] bf16
// [1780,2292): gate/tanh projections
__global__ void prep_fused(const float* __restrict__ e1, const float* __restrict__ e2,
                           const float* __restrict__ Wb,
                           const float* __restrict__ Wd, const float* __restrict__ Wg,
                           unsigned short* __restrict__ e1b, unsigned short* __restrict__ e2b,
                           unsigned short* __restrict__ wbt,
                           float* __restrict__ p1d, float* __restrict__ p1g,
                           float* __restrict__ p2d, float* __restrict__ p2g) {
    const int blk = blockIdx.x;
    __shared__ float tile[32][33];

    if (blk < 1280) {
        // ---- convert arm ----
        int gid = blk * 256 + threadIdx.x;     // 8192 rows * 40 granules
        int row = gid / 40;
        int d0 = (gid % 40) * 8;
        const float* src;
        unsigned short* dst;
        if (row < 4096) { src = e1 + (size_t)row * DDIM; dst = e1b + (size_t)row * DP + d0; }
        else { int r = row - 4096; src = e2 + (size_t)r * DDIM; dst = e2b + (size_t)r * DP + d0; }
        float v[8];
        if (d0 + 8 <= DDIM) {
            float4 lo = *(const float4*)(src + d0);
            float4 hi = *(const float4*)(src + d0 + 4);
            v[0] = lo.x; v[1] = lo.y; v[2] = lo.z; v[3] = lo.w;
            v[4] = hi.x; v[5] = hi.y; v[6] = hi.z; v[7] = hi.w;
        } else if (d0 < DDIM) {             // d0 == 296
            float4 lo = *(const float4*)(src + d0);
            v[0] = lo.x; v[1] = lo.y; v[2] = lo.z; v[3] = lo.w;
            v[4] = v[5] = v[6] = v[7] = 0.f;
        } else {
            for (int j = 0; j < 8; ++j) v[j] = 0.f;
        }
        unsigned short tmp[8];
#pragma unroll
        for (int j = 0; j < 8; ++j) tmp[j] = f2bf(v[j]);
        *(short8*)dst = *(short8*)tmp;
    } else if (blk < 1780) {
        // ---- Wb transpose arm: idx -> (k, e-tile); dt loop inside ----
        int idx = blk - 1280;
        int k = idx / 10, et = idx % 10;
        int tx = threadIdx.x & 31, ty = threadIdx.x >> 5;
        for (int dt = 0; dt < 10; ++dt) {
#pragma unroll
            for (int rr = 0; rr < 4; ++rr) {
                int d = dt * 32 + ty + rr * 8;
                int e = et * 32 + tx;
                tile[ty + rr * 8][tx] = (d < DDIM && e < DDIM) ? Wb[((size_t)k * DDIM + d) * DDIM + e] : 0.f;
            }
            __syncthreads();
#pragma unroll
            for (int rr = 0; rr < 4; ++rr) {
                int e = et * 32 + ty + rr * 8;
                int d = dt * 32 + tx;
                wbt[((size_t)k * DP + e) * DP + d] = f2bf(tile[tx][ty + rr * 8]);
            }
            __syncthreads();
        }
    } else {
        // ---- projection arm: 512 blocks, 16 rows each ----
        int bid = blk - 1780;
        const int kk = threadIdx.x & 63;
        const int grp = threadIdx.x >> 6;
        const int kks = kk < KDIM ? kk : 0;
        const float* src; int woff; float *dd, *dg; int r0;
        int rowbase = bid * 16;
        if (rowbase < 4096) { r0 = rowbase; src = e1; woff = 0; dd = p1d; dg = p1g; }
        else { r0 = rowbase - 4096; src = e2; woff = DDIM; dd = p2d; dg = p2g; }
        const float* e0 = src + (size_t)(r0 + grp * 4) * DDIM;
        const float* wdp = Wd + (size_t)woff * KDIM + kks;
        const float* wgp = Wg + (size_t)woff * KDIM + kks;

        float ad[4] = {0.f, 0.f, 0.f, 0.f}, ag[4] = {0.f, 0.f, 0.f, 0.f};
        for (int c = 0; c < DDIM / 4; ++c) {
            const int d0 = c * 4;
            float4 x[4];
#pragma unroll
            for (int rr = 0; rr < 4; ++rr)
                x[rr] = *(const float4*)(e0 + (size_t)rr * DDIM + d0);
            float wd0 = wdp[(size_t)(d0 + 0) * KDIM];
            float wd1 = wdp[(size_t)(d0 + 1) * KDIM];
            float wd2 = wdp[(size_t)(d0 + 2) * KDIM];
            float wd3 = wdp[(size_t)(d0 + 3) * KDIM];
            float wg0 = wgp[(size_t)(d0 + 0) * KDIM];
            float wg1 = wgp[(size_t)(d0 + 1) * KDIM];
            float wg2 = wgp[(size_t)(d0 + 2) * KDIM];
            float wg3 = wgp[(size_t)(d0 + 3) * KDIM];
#pragma unroll
            for (int rr = 0; rr < 4; ++rr) {
                ad[rr] += x[rr].x * wd0 + x[rr].y * wd1 + x[rr].z * wd2 + x[rr].w * wd3;
                ag[rr] += x[rr].x * wg0 + x[rr].y * wg1 + x[rr].z * wg2 + x[rr].w * wg3;
            }
        }
        if (kk < KDIM) {
#pragma unroll
            for (int rr = 0; rr < 4; ++rr) {
                size_t o = (size_t)(r0 + grp * 4 + rr) * KDIM + kk;
                dd[o] = ad[rr];
                dg[o] = ag[rr];
            }
        }
    }
}

// ---------- main: barrier-free K-loop ----------
// Wb and e2 MFMA fragments read DIRECTLY from global (addresses are wave-invariant
// within a block -> L1 serves the 4x re-read). Only the wave-private T round-trip
// uses LDS (no __syncthreads needed: per-wave DS ops are in-order). Phase 1 uses
// A=Wb, B=e1 so T is written as 4x ds_write_b64 (C rows = 4 consecutive e').
template <int SLAB>
__global__ __launch_bounds__(256, 2) void grn_main(
    const unsigned short* __restrict__ e1b, const unsigned short* __restrict__ e2b,
    const unsigned short* __restrict__ wbt,
    const float* __restrict__ p1d, const float* __restrict__ p1g,
    const float* __restrict__ p2d, const float* __restrict__ p2g,
    const float* __restrict__ bg, const float* __restrict__ bb,
    const float* __restrict__ u, float* __restrict__ out) {
    const int b = blockIdx.x, k = blockIdx.y;
    const int tid = threadIdx.x;
    const int wid = tid >> 6, lane = tid & 63;
    const int q = lane >> 4, ln = lane & 15;
    const int rw0 = wid * 32;                      // wave owns i-rows [rw0, rw0+32)

    __shared__ __align__(16) unsigned short Tt[LL * TP];   // 10240B, wave-private rows
    __shared__ float pbuf[4][LL];

    if (tid < LL) {
        int gi = (b * LL + tid) * KDIM + k;
        pbuf[0][tid] = p1d[gi];
        pbuf[1][tid] = p1g[gi];
        pbuf[2][tid] = p2d[gi];
        pbuf[3][tid] = p2g[gi];
    }
    const float u_k = u[k], bg_k = bg[k], b_k = bb[k];

    // e1 B-fragments: lane holds e1[i=rw0+mt*16+ln][d=kd*32+q*8+j]; reused 10x
    short8 af[2][10];
#pragma unroll
    for (int mt = 0; mt < 2; ++mt) {
        const unsigned short* p = e1b + ((size_t)(b * LL + rw0 + mt * 16 + ln)) * DP + q * 8;
#pragma unroll
        for (int kd = 0; kd < 10; ++kd)
            af[mt][kd] = *(const short8*)(p + kd * 32);
    }
    __syncthreads();   // pbuf ready (the only block-wide barrier)

    const unsigned short* wrow0 = wbt + (size_t)k * DP * DP + (size_t)ln * DP + q * 8;
    const unsigned short* erow  = e2b + ((size_t)(b * LL + ln)) * DP + q * 8;
    char* twr = (char*)Tt + (rw0 + ln) * 80;

    float4v S[2][8];
#pragma unroll
    for (int mt = 0; mt < 2; ++mt)
#pragma unroll
        for (int nt = 0; nt < 8; ++nt)
            S[mt][nt] = (float4v){0.f, 0.f, 0.f, 0.f};

#pragma unroll 1
    for (int et = 0; et < 10; ++et) {
        const int e0 = et * 32;
        // phase 1: T[e'][i] = sum_d Wb[e'][d] * e1[i][d]  (A=Wb rows e', B=e1 rows i)
        float4v tacc[2][2];
#pragma unroll
        for (int emt = 0; emt < 2; ++emt)
#pragma unroll
            for (int imt = 0; imt < 2; ++imt)
                tacc[emt][imt] = (float4v){0.f, 0.f, 0.f, 0.f};
#pragma unroll
        for (int kd = 0; kd < 10; ++kd) {
            short8 wa0 = *(const short8*)(wrow0 + (size_t)(e0) * DP + kd * 32);
            short8 wa1 = *(const short8*)(wrow0 + (size_t)(e0 + 16) * DP + kd * 32);
            tacc[0][0] = mfma16(wa0, af[0][kd], tacc[0][0]);
            tacc[0][1] = mfma16(wa0, af[1][kd], tacc[0][1]);
            tacc[1][0] = mfma16(wa1, af[0][kd], tacc[1][0]);
            tacc[1][1] = mfma16(wa1, af[1][kd], tacc[1][1]);
        }
        // T write: tacc[emt][imt][r] = T[e'=emt*16+q*4+r][i=rw0+imt*16+ln]
        //  -> Tt[i][e'], 4 consecutive e' per b64, wave-private rows
#pragma unroll
        for (int imt = 0; imt < 2; ++imt) {
            char* tw = twr + imt * (16 * 80) + q * 8;
#pragma unroll
            for (int emt = 0; emt < 2; ++emt) {
                uint2 v;
                v.x = pack2bf(tacc[emt][imt][0], tacc[emt][imt][1]);
                v.y = pack2bf(tacc[emt][imt][2], tacc[emt][imt][3]);
                *(uint2*)(tw + emt * 32) = v;
            }
        }
        // phase 2: S[i][j] += sum_e' T[i][e'] * e2[j][e0+e']
        short8 a0 = *(const short8*)(twr + q * 16);
        short8 a1 = *(const short8*)(twr + 16 * 80 + q * 16);
#pragma unroll
        for (int nt = 0; nt < 8; ++nt) {
            short8 bf = *(const short8*)(erow + (size_t)(nt * 16) * DP + e0);
            S[0][nt] = mfma16(a0, bf, S[0][nt]);
            S[1][nt] = mfma16(a1, bf, S[1][nt]);
        }
    }

    // epilogue: gate, mix, scale by u[k]; slab plain stores (or atomic fallback)
    float pdi[2][4], pgi[2][4];
#pragma unroll
    for (int mt = 0; mt < 2; ++mt)
#pragma unroll
        for (int r = 0; r < 4; ++r) {
            int i = rw0 + mt * 16 + q * 4 + r;
            pdi[mt][r] = pbuf[0][i];
            pgi[mt][r] = pbuf[1][i];
        }
    float* dst = SLAB ? (out + ((size_t)k * NB + b) * (LL * LL))
                      : (out + (size_t)b * LL * LL);
#pragma unroll
    for (int nt = 0; nt < 8; ++nt) {
        int j = nt * 16 + ln;
        float pdj = pbuf[2][j];
        float pgj = pbuf[3][j] + bg_k;
#pragma unroll
        for (int mt = 0; mt < 2; ++mt)
#pragma unroll
            for (int r = 0; r < 4; ++r) {
                int i = rw0 + mt * 16 + q * 4 + r;
                float btp = S[mt][nt][r];
                float sd = pdi[mt][r] + pdj;
                float sg = pgi[mt][r] + pgj;
                float e2x = __expf(2.f * sd);
                float sln = 1.f - 2.f * __builtin_amdgcn_rcpf(e2x + 1.f);   // tanh(sd)
                float g = __builtin_amdgcn_rcpf(1.f + __expf(-sg));          // sigmoid(sg)
                float val = u_k * (g * btp + (1.f - g) * sln + b_k);
                if (SLAB) dst[(size_t)i * LL + j] = val;
                else      unsafeAtomicAdd(dst + (size_t)i * LL + j, val);
            }
    }
}

// ---------- reduce: out[x] = sum_k slab[k][x], float4 ----------
__global__ void reduce_k(const float* __restrict__ slab, float* __restrict__ out) {
    int idx = blockIdx.x * 256 + threadIdx.x;     // 0..131071 float4s
    const float4* s4 = (const float4*)slab;
    float4 a0 = {0.f, 0.f, 0.f, 0.f}, a1 = {0.f, 0.f, 0.f, 0.f};
#pragma unroll
    for (int k = 0; k < KDIM; k += 2) {
        float4 x = s4[(size_t)k * 131072 + idx];
        float4 y = s4[(size_t)(k + 1) * 131072 + idx];
        a0.x += x.x; a0.y += x.y; a0.z += x.z; a0.w += x.w;
        a1.x += y.x; a1.y += y.y; a1.z += y.z; a1.w += y.w;
    }
    float4 r;
    r.x = a0.x + a1.x; r.y = a0.y + a1.y; r.z = a0.z + a1.z; r.w = a0.w + a1.w;
    ((float4*)out)[idx] = r;
}

extern "C" void kernel_launch(void* const* d_in, const int* in_sizes, int n_in,
                              void* d_out, int out_size, void* d_ws, size_t ws_size,
                              hipStream_t stream) {
    const float* e1 = (const float*)d_in[0];   // (32,128,300)
    const float* e2 = (const float*)d_in[1];   // (32,128,300)
    const float* Wb = (const float*)d_in[2];   // (50,300,300)
    const float* Wd = (const float*)d_in[3];   // (600,50)
    const float* Wg = (const float*)d_in[4];   // (600,50)
    const float* bg = (const float*)d_in[5];   // (50,)
    const float* bb = (const float*)d_in[6];   // (50,)
    const float* u  = (const float*)d_in[7];   // (50,1)
    float* out = (float*)d_out;                // (32,128,128,1)

    unsigned short* e1b = (unsigned short*)d_ws;                 // 1,310,720 elems
    unsigned short* e2b = e1b + 1310720;                         // 1,310,720 elems
    unsigned short* wbt = e2b + 1310720;                         // 5,120,000 elems
    float* pf  = (float*)((char*)d_ws + 15482880);
    float* p1d = pf;
    float* p1g = pf + 204800;
    float* p2d = pf + 409600;
    float* p2g = pf + 614400;                                    // end 18,759,680 B
    float* slab = (float*)((char*)d_ws + SLAB_OFF);              // 50 x 524288 floats

    prep_fused<<<2292, 256, 0, stream>>>(e1, e2, Wb, Wd, Wg,
                                         e1b, e2b, wbt,
                                         p1d, p1g, p2d, p2g);

    if (ws_size >= WS_NEED) {
        grn_main<1><<<dim3(NB, KDIM), 256, 0, stream>>>(e1b, e2b, wbt,
                                                        p1d, p1g, p2d, p2g,
                                                        bg, bb, u, slab);
        reduce_k<<<512, 256, 0, stream>>>(slab, out);
    } else {
        hipMemsetAsync(d_out, 0, (size_t)out_size * sizeof(float), stream);
        grn_main<0><<<dim3(NB, KDIM), 256, 0, stream>>>(e1b, e2b, wbt,
                                                        p1d, p1g, p2d, p2g,
                                                        bg, bb, u, out);
    }
}

// Round 8
// 234.599 us; speedup vs baseline: 1.8355x; 1.8355x over previous
//
#include <hip/hip_runtime.h>
#include <hip/hip_bf16.h>

typedef __attribute__((ext_vector_type(8))) short short8;
typedef __attribute__((ext_vector_type(4))) float float4v;
typedef _Float16 half4v __attribute__((ext_vector_type(4)));

#define NB 32
#define LL 128
#define DDIM 300
#define DP 320
#define KDIM 50
#define WP 328   // wtile pitch (bf16 elems)
#define TP 40    // T/e2t pitch
#define SLAB_OFF 18759680ull
#define SLAB_BYTES (50ull * 32ull * 16384ull * 2ull)          // 52,428,800
#define WS_NEED  (SLAB_OFF + SLAB_BYTES)

__device__ __forceinline__ unsigned short f2bf(float x) {
    unsigned int u = __float_as_uint(x);
    unsigned int r = (u + 0x7FFFu + ((u >> 16) & 1u)) >> 16;
    return (unsigned short)r;
}
__device__ __forceinline__ unsigned int pack2bf(float a, float b) {
    return (unsigned int)f2bf(a) | ((unsigned int)f2bf(b) << 16);
}
__device__ __forceinline__ float4v mfma16(short8 a, short8 b, float4v c) {
    return __builtin_amdgcn_mfma_f32_16x16x32_bf16(a, b, c, 0, 0, 0);
}

// ---------- prep: gate/tanh projections + e->bf16 conversion (fused; rows L1-hot) ----------
__global__ void prep_pc(const float* __restrict__ e1, const float* __restrict__ e2,
                        const float* __restrict__ Wd, const float* __restrict__ Wg,
                        float* __restrict__ p1d, float* __restrict__ p1g,
                        float* __restrict__ p2d, float* __restrict__ p2g,
                        unsigned short* __restrict__ e1b, unsigned short* __restrict__ e2b) {
    const int bid = blockIdx.x;                 // 0..511, 16 rows each
    const int kk = threadIdx.x & 63;
    const int grp = threadIdx.x >> 6;           // 0..3 -> 4 rows each
    const int kks = kk < KDIM ? kk : 0;
    const float* src; int woff; float *dd, *dg; int r0;
    unsigned short* bdst;
    int rowbase = bid * 16;
    if (rowbase < 4096) { r0 = rowbase; src = e1; woff = 0; dd = p1d; dg = p1g; bdst = e1b; }
    else { r0 = rowbase - 4096; src = e2; woff = DDIM; dd = p2d; dg = p2g; bdst = e2b; }
    const float* e0 = src + (size_t)(r0 + grp * 4) * DDIM;
    const float* wdp = Wd + (size_t)woff * KDIM + kks;
    const float* wgp = Wg + (size_t)woff * KDIM + kks;

    float ad[4] = {0.f, 0.f, 0.f, 0.f}, ag[4] = {0.f, 0.f, 0.f, 0.f};
    for (int c = 0; c < DDIM / 4; ++c) {
        const int d0 = c * 4;
        float4 x[4];
#pragma unroll
        for (int rr = 0; rr < 4; ++rr)
            x[rr] = *(const float4*)(e0 + (size_t)rr * DDIM + d0);
        float wd0 = wdp[(size_t)(d0 + 0) * KDIM];
        float wd1 = wdp[(size_t)(d0 + 1) * KDIM];
        float wd2 = wdp[(size_t)(d0 + 2) * KDIM];
        float wd3 = wdp[(size_t)(d0 + 3) * KDIM];
        float wg0 = wgp[(size_t)(d0 + 0) * KDIM];
        float wg1 = wgp[(size_t)(d0 + 1) * KDIM];
        float wg2 = wgp[(size_t)(d0 + 2) * KDIM];
        float wg3 = wgp[(size_t)(d0 + 3) * KDIM];
#pragma unroll
        for (int rr = 0; rr < 4; ++rr) {
            ad[rr] += x[rr].x * wd0 + x[rr].y * wd1 + x[rr].z * wd2 + x[rr].w * wd3;
            ag[rr] += x[rr].x * wg0 + x[rr].y * wg1 + x[rr].z * wg2 + x[rr].w * wg3;
        }
    }
    if (kk < KDIM) {
#pragma unroll
        for (int rr = 0; rr < 4; ++rr) {
            size_t o = (size_t)(r0 + grp * 4 + rr) * KDIM + kk;
            dd[o] = ad[rr];
            dg[o] = ag[rr];
        }
    }
    // conversion arm: this block's 16 rows -> bf16 padded (640 granules of 8)
    for (int it = 0; it < 3; ++it) {
        int g = threadIdx.x + it * 256;
        if (g >= 640) break;
        int rl = g / 40, d0 = (g % 40) * 8;
        const float* sp = src + (size_t)(r0 + rl) * DDIM;
        unsigned short* dp = bdst + (size_t)(r0 + rl) * DP + d0;
        float v[8];
        if (d0 + 8 <= DDIM) {
            float4 lo = *(const float4*)(sp + d0);
            float4 hi = *(const float4*)(sp + d0 + 4);
            v[0] = lo.x; v[1] = lo.y; v[2] = lo.z; v[3] = lo.w;
            v[4] = hi.x; v[5] = hi.y; v[6] = hi.z; v[7] = hi.w;
        } else if (d0 < DDIM) {          // d0 == 296
            float4 lo = *(const float4*)(sp + d0);
            v[0] = lo.x; v[1] = lo.y; v[2] = lo.z; v[3] = lo.w;
            v[4] = v[5] = v[6] = v[7] = 0.f;
        } else {
            for (int j = 0; j < 8; ++j) v[j] = 0.f;
        }
        unsigned short tmp[8];
#pragma unroll
        for (int j = 0; j < 8; ++j) tmp[j] = f2bf(v[j]);
        *(short8*)dp = *(short8*)tmp;
    }
}

// ---------- prep: Wb (k,d,e) fp32 -> Wbt (k,e,d) bf16, padded to 320x320 ----------
__global__ void prep_wbt(const float* __restrict__ Wb, unsigned short* __restrict__ wbt) {
    int k = blockIdx.x, et = blockIdx.y;
    int tx = threadIdx.x & 31, ty = threadIdx.x >> 5;   // ty 0..7
    __shared__ float tile[32][33];
    for (int dt = 0; dt < 10; ++dt) {
#pragma unroll
        for (int rr = 0; rr < 4; ++rr) {
            int d = dt * 32 + ty + rr * 8;
            int e = et * 32 + tx;
            tile[ty + rr * 8][tx] = (d < DDIM && e < DDIM) ? Wb[((size_t)k * DDIM + d) * DDIM + e] : 0.f;
        }
        __syncthreads();
#pragma unroll
        for (int rr = 0; rr < 4; ++rr) {
            int e = et * 32 + ty + rr * 8;
            int d = dt * 32 + tx;
            wbt[((size_t)k * DP + e) * DP + d] = f2bf(tile[tx][ty + rr * 8]);
        }
        __syncthreads();
    }
}

// ---------- main: per (b,k): S = (e1 Wb[k]) e2^T, gate;
// R6 staging structure + phase-1 operand swap (A=Wb,B=e1 -> b64 T-writes).
// SLAB=1: coalesced fp16 stores to permuted slab. SLAB=0: fp32 atomics to out. ----------
template <int SLAB>
__global__ __launch_bounds__(256, 2) void grn_main(
    const unsigned short* __restrict__ e1b, const unsigned short* __restrict__ e2b,
    const unsigned short* __restrict__ wbt,
    const float* __restrict__ p1d, const float* __restrict__ p1g,
    const float* __restrict__ p2d, const float* __restrict__ p2g,
    const float* __restrict__ bg, const float* __restrict__ bb,
    const float* __restrict__ u, float* __restrict__ out, _Float16* __restrict__ slab) {
    const int b = blockIdx.x, k = blockIdx.y;
    const int tid = threadIdx.x;
    const int wid = tid >> 6, lane = tid & 63;
    const int q = lane >> 4, ln = lane & 15;
    const int rw0 = wid * 32;                      // wave owns i-rows [rw0, rw0+32)

    __shared__ __align__(16) unsigned short wtile[32 * WP];   // Wbt tile [e'][d]
    __shared__ __align__(16) unsigned short Tt[128 * TP];     // T tile   [i][e']
    __shared__ __align__(16) unsigned short e2t[128 * TP];    // e2 tile  [j][e']
    __shared__ float pbuf[4][128];

    if (tid < 128) {
        int gi = (b * LL + tid) * KDIM + k;
        pbuf[0][tid] = p1d[gi];
        pbuf[1][tid] = p1g[gi];
        pbuf[2][tid] = p2d[gi];
        pbuf[3][tid] = p2g[gi];
    }
    const float u_k = u[k], bg_k = bg[k], b_k = bb[k];

    const unsigned short* wbt_k = wbt + (size_t)k * DP * DP;
    size_t wgo[5]; int wlo[5];
#pragma unroll
    for (int it = 0; it < 5; ++it) {
        int c = tid + it * 256, r = c / 40, col = (c % 40) * 8;
        wgo[it] = (size_t)r * DP + col;
        wlo[it] = r * WP + col;
    }
    size_t ego[2]; int elo[2];
#pragma unroll
    for (int it = 0; it < 2; ++it) {
        int c = tid + it * 256, j = c >> 2, col = (c & 3) * 8;
        ego[it] = (size_t)(b * LL + j) * DP + col;
        elo[it] = j * TP + col;
    }

    // e1 B-fragments: lane holds e1[i=rw0+mt*16+ln][d=kd*32+q*8+j]; reused 10x
    short8 af[2][10];
#pragma unroll
    for (int mt = 0; mt < 2; ++mt) {
        const unsigned short* p = e1b + ((size_t)(b * LL + rw0 + mt * 16 + ln)) * DP + q * 8;
#pragma unroll
        for (int kd = 0; kd < 10; ++kd)
            af[mt][kd] = *(const short8*)(p + kd * 32);
    }

    float4v S[2][8];
#pragma unroll
    for (int mt = 0; mt < 2; ++mt)
#pragma unroll
        for (int nt = 0; nt < 8; ++nt)
            S[mt][nt] = (float4v){0.f, 0.f, 0.f, 0.f};

    // prefetch tile 0
    short8 wpre[5], epre[2];
#pragma unroll
    for (int it = 0; it < 5; ++it) wpre[it] = *(const short8*)(wbt_k + wgo[it]);
#pragma unroll
    for (int it = 0; it < 2; ++it) epre[it] = *(const short8*)(e2b + ego[it]);

    char* twr = (char*)Tt + (rw0 + ln) * 80;

    for (int et = 0; et < 10; ++et) {
#pragma unroll
        for (int it = 0; it < 5; ++it) *(short8*)&wtile[wlo[it]] = wpre[it];
#pragma unroll
        for (int it = 0; it < 2; ++it) *(short8*)&e2t[elo[it]] = epre[it];
        __syncthreads();

        if (et < 9) {
            const size_t ew = (size_t)(et + 1) * 32 * DP;
            const int ee = (et + 1) * 32;
#pragma unroll
            for (int it = 0; it < 5; ++it) wpre[it] = *(const short8*)(wbt_k + ew + wgo[it]);
#pragma unroll
            for (int it = 0; it < 2; ++it) epre[it] = *(const short8*)(e2b + ego[it] + ee);
        }

        // phase 1: T[e'][i] = sum_d Wb[e'][d]*e1[i][d]; A=wtile rows e', B=af rows i
        float4v tacc[2][2];   // [emt][imt]
#pragma unroll
        for (int emt = 0; emt < 2; ++emt)
#pragma unroll
            for (int imt = 0; imt < 2; ++imt)
                tacc[emt][imt] = (float4v){0.f, 0.f, 0.f, 0.f};
#pragma unroll
        for (int kd = 0; kd < 10; ++kd) {
            short8 wa0 = *(const short8*)&wtile[(ln) * WP + kd * 32 + q * 8];
            short8 wa1 = *(const short8*)&wtile[(16 + ln) * WP + kd * 32 + q * 8];
            tacc[0][0] = mfma16(wa0, af[0][kd], tacc[0][0]);
            tacc[0][1] = mfma16(wa0, af[1][kd], tacc[0][1]);
            tacc[1][0] = mfma16(wa1, af[0][kd], tacc[1][0]);
            tacc[1][1] = mfma16(wa1, af[1][kd], tacc[1][1]);
        }
        // T write: tacc[emt][imt][r] = T[e'=emt*16+q*4+r][i=rw0+imt*16+ln]
        //  -> Tt[i][e'], one b64 per (imt,emt); wave-private rows
#pragma unroll
        for (int imt = 0; imt < 2; ++imt) {
            char* tw = twr + imt * (16 * 80) + q * 8;
#pragma unroll
            for (int emt = 0; emt < 2; ++emt) {
                uint2 v;
                v.x = pack2bf(tacc[emt][imt][0], tacc[emt][imt][1]);
                v.y = pack2bf(tacc[emt][imt][2], tacc[emt][imt][3]);
                *(uint2*)(tw + emt * 32) = v;
            }
        }
        // phase 2: S[i][j] += sum_e' T[i][e'] * e2t[j][e']
        short8 a0 = *(const short8*)(twr + q * 16);
        short8 a1 = *(const short8*)(twr + 16 * 80 + q * 16);
#pragma unroll
        for (int nt = 0; nt < 8; ++nt) {
            short8 bf = *(const short8*)&e2t[(nt * 16 + ln) * TP + q * 8];
            S[0][nt] = mfma16(a0, bf, S[0][nt]);
            S[1][nt] = mfma16(a1, bf, S[1][nt]);
        }
        __syncthreads();
    }

    // epilogue: gate, mix, scale by u[k]
    float pdi[2][4], pgi[2][4];
#pragma unroll
    for (int mt = 0; mt < 2; ++mt)
#pragma unroll
        for (int r = 0; r < 4; ++r) {
            int i = rw0 + mt * 16 + q * 4 + r;
            pdi[mt][r] = pbuf[0][i];
            pgi[mt][r] = pbuf[1][i];
        }
    _Float16* sdst = slab + ((size_t)k * NB + b) * 16384;
    float* adst = out + (size_t)b * LL * LL;
#pragma unroll
    for (int nt = 0; nt < 8; ++nt) {
        int j = nt * 16 + ln;
        float pdj = pbuf[2][j];
        float pgj = pbuf[3][j] + bg_k;
#pragma unroll
        for (int mt = 0; mt < 2; ++mt)
#pragma unroll
            for (int r = 0; r < 4; ++r) {
                int i = rw0 + mt * 16 + q * 4 + r;
                float btp = S[mt][nt][r];
                float sd = pdi[mt][r] + pdj;
                float sg = pgi[mt][r] + pgj;
                float e2x = __expf(2.f * sd);
                float sln = 1.f - 2.f * __builtin_amdgcn_rcpf(e2x + 1.f);   // tanh(sd)
                float g = __builtin_amdgcn_rcpf(1.f + __expf(-sg));          // sigmoid(sg)
                float val = u_k * (g * btp + (1.f - g) * sln + b_k);
                if (SLAB) {
                    // permuted layout: pos = v*256 + tid, v = nt*8+mt*4+r (coalesced)
                    sdst[(nt * 8 + mt * 4 + r) * 256 + tid] = (_Float16)val;
                } else {
                    unsafeAtomicAdd(adst + (size_t)i * LL + j, val);
                }
            }
    }
}

// ---------- reduce: out[b][i][j] = sum_k slab[k][b][pos]; decode permutation ----------
__global__ void reduce_k(const _Float16* __restrict__ slab, float* __restrict__ out) {
    int idx = blockIdx.x * 256 + threadIdx.x;     // 0..131071
    int b = idx >> 12;                            // 4096 thread-groups per b
    int p4 = idx & 4095;
    int pos0 = p4 * 4;
    int v = pos0 >> 8, tid0 = pos0 & 255;
    int nt = v >> 3, mt = (v >> 2) & 1, r = v & 3;
    int wid = tid0 >> 6, q = (tid0 >> 4) & 3, ln0 = tid0 & 15;
    int i = wid * 32 + mt * 16 + q * 4 + r;
    int j0 = nt * 16 + ln0;

    float a0 = 0.f, a1 = 0.f, a2 = 0.f, a3 = 0.f;
    const _Float16* sp = slab + (size_t)b * 16384 + pos0;
#pragma unroll
    for (int k = 0; k < KDIM; ++k) {
        half4v h = *(const half4v*)(sp + (size_t)k * (NB * 16384));
        a0 += (float)h[0]; a1 += (float)h[1]; a2 += (float)h[2]; a3 += (float)h[3];
    }
    float4 rv; rv.x = a0; rv.y = a1; rv.z = a2; rv.w = a3;
    *(float4*)(out + (size_t)b * 16384 + i * 128 + j0) = rv;
}

extern "C" void kernel_launch(void* const* d_in, const int* in_sizes, int n_in,
                              void* d_out, int out_size, void* d_ws, size_t ws_size,
                              hipStream_t stream) {
    const float* e1 = (const float*)d_in[0];   // (32,128,300)
    const float* e2 = (const float*)d_in[1];   // (32,128,300)
    const float* Wb = (const float*)d_in[2];   // (50,300,300)
    const float* Wd = (const float*)d_in[3];   // (600,50)
    const float* Wg = (const float*)d_in[4];   // (600,50)
    const float* bg = (const float*)d_in[5];   // (50,)
    const float* bb = (const float*)d_in[6];   // (50,)
    const float* u  = (const float*)d_in[7];   // (50,1)
    float* out = (float*)d_out;                // (32,128,128,1)

    unsigned short* e1b = (unsigned short*)d_ws;                 // 1,310,720 elems
    unsigned short* e2b = e1b + 1310720;                         // 1,310,720 elems
    unsigned short* wbt = e2b + 1310720;                         // 5,120,000 elems
    float* pf  = (float*)((char*)d_ws + 15482880);
    float* p1d = pf;
    float* p1g = pf + 204800;
    float* p2d = pf + 409600;
    float* p2g = pf + 614400;                                    // end 18,759,680 B
    _Float16* slab = (_Float16*)((char*)d_ws + SLAB_OFF);        // 50x32x16384 halves

    prep_pc<<<512, 256, 0, stream>>>(e1, e2, Wd, Wg, p1d, p1g, p2d, p2g, e1b, e2b);
    prep_wbt<<<dim3(KDIM, 10), 256, 0, stream>>>(Wb, wbt);

    if (ws_size >= WS_NEED) {
        grn_main<1><<<dim3(NB, KDIM), 256, 0, stream>>>(e1b, e2b, wbt,
                                                        p1d, p1g, p2d, p2g,
                                                        bg, bb, u, out, slab);
        reduce_k<<<512, 256, 0, stream>>>(slab, out);
    } else {
        hipMemsetAsync(d_out, 0, (size_t)out_size * sizeof(float), stream);
        grn_main<0><<<dim3(NB, KDIM), 256, 0, stream>>>(e1b, e2b, wbt,
                                                        p1d, p1g, p2d, p2g,
                                                        bg, bb, u, out, slab);
    }
}